// Round 12
// baseline (187.204 us; speedup 1.0000x reference)
//
#include <hip/hip_runtime.h>
#include <hip/hip_bf16.h>

#define V_SIZE 32000
#define SEQ 64
#define BATCH 64
#define EMB 32
#define HID 16
#define NROWS (SEQ * BATCH)   // 4096
#define V4 (V_SIZE / 4)       // 8000 float4 columns
#define STRIPS 32             // k_write: 32 strips * 256 f4-cols
#define CHUNKS 64
#define ROWS_W (NROWS / CHUNKS)   // 64 rows per chunk
#define RGROUP 8                  // rows per inner group in k_write
#define NRB (NROWS / 16)          // 256 row-blocks (MFMA M-tiles)
#define NTILES (V_SIZE / 16)      // 2000 col-tiles (MFMA N-tiles)
#define RBW 4                     // row-blocks per wave (b-frag reuse)
#define NRG (NRB / RBW)           // 64 row-groups
#define XSTRIPS 100               // expsum strips
#define TPW (NTILES / XSTRIPS)    // 20 tiles per wave
#define NSLOTS XSTRIPS

typedef float f32x4 __attribute__((ext_vector_type(4)));
typedef short short8 __attribute__((ext_vector_type(8)));

__device__ inline short bf16_rne(float x) {
    unsigned u = __builtin_bit_cast(unsigned, x);
    unsigned r = u + 0x7FFFu + ((u >> 16) & 1u);
    return (short)(r >> 16);
}

// ---------------------------------------------------------------------------
// Kernel A: h_table[r][j] = sigmoid(lookup[idx[r]].wx[:,j] + (h0@wh)[j])
// Also emits bf16 A-fragments (16x16x32, K padded 16->32).
// ---------------------------------------------------------------------------
__global__ __launch_bounds__(256) void k_htable(
    const int* __restrict__ idx, const float* __restrict__ lookup,
    const float* __restrict__ wx, const float* __restrict__ wh,
    const float* __restrict__ h0, float* __restrict__ h_table,
    short* __restrict__ a_frag)
{
    int r = blockIdx.x * 256 + threadIdx.x;
    if (r >= NROWS) return;

    float acc[HID];
    #pragma unroll
    for (int j = 0; j < HID; ++j) acc[j] = 0.f;

    #pragma unroll
    for (int i = 0; i < HID; ++i) {
        float h0i = h0[i];
        #pragma unroll
        for (int j = 0; j < HID; ++j) acc[j] += h0i * wh[i * HID + j];
    }

    int tok = idx[r];
    const float* xrow = lookup + (long)tok * EMB;
    #pragma unroll
    for (int e = 0; e < EMB; ++e) {
        float x = xrow[e];
        #pragma unroll
        for (int j = 0; j < HID; ++j) acc[j] += x * wx[e * HID + j];
    }

    float h[HID];
    #pragma unroll
    for (int j = 0; j < HID; ++j) {
        h[j] = 1.f / (1.f + __expf(-acc[j]));
        h_table[r * HID + j] = h[j];
    }

    const int rb = r >> 4;
    const int m  = r & 15;
    short8 lo, hi, zz;
    #pragma unroll
    for (int j = 0; j < 8; ++j) {
        lo[j] = bf16_rne(h[j]);
        hi[j] = bf16_rne(h[j + 8]);
        zz[j] = 0;
    }
    short8* af = reinterpret_cast<short8*>(a_frag);
    af[rb * 64 + m]      = lo;   // lanes 0..15:  k = 0..7
    af[rb * 64 + m + 16] = hi;   // lanes 16..31: k = 8..15
    af[rb * 64 + m + 32] = zz;   // pad
    af[rb * 64 + m + 48] = zz;   // pad
}

// ---------------------------------------------------------------------------
// Kernel A2: pack Wo into bf16 B-fragments (same slot->k convention as A).
// ---------------------------------------------------------------------------
__global__ __launch_bounds__(256) void k_wpack(
    const float* __restrict__ wo, short* __restrict__ b_frag)
{
    int gid = blockIdx.x * 256 + threadIdx.x;   // 2000*64 threads
    if (gid >= NTILES * 64) return;
    const int t = gid >> 6;
    const int l = gid & 63;
    const int col = t * 16 + (l & 15);

    short8 b;
    if (l < 32) {
        const int k0 = (l >> 4) * 8;
        #pragma unroll
        for (int j = 0; j < 8; ++j)
            b[j] = bf16_rne(wo[(size_t)(k0 + j) * V_SIZE + col]);
    } else {
        #pragma unroll
        for (int j = 0; j < 8; ++j) b[j] = 0;
    }
    reinterpret_cast<short8*>(b_frag)[gid] = b;
}

// ---------------------------------------------------------------------------
// Kernel B: MFMA exp-sum, RBW=4 row-blocks per wave + prefetch-2 pipeline.
// One b-frag load feeds 4 MFMAs (b-frag L2 traffic 512 MB -> 128 MB).
// C/D layout (m89-verified): col=lane&15, row=(lane>>4)*4+reg.
// ---------------------------------------------------------------------------
__global__ __launch_bounds__(256) void k_expsum(
    const short* __restrict__ a_frag, const short* __restrict__ b_frag,
    float* __restrict__ partial)
{
    const int lane = threadIdx.x & 63;
    const int wid  = threadIdx.x >> 6;
    const int g = blockIdx.x * 4 + wid;      // 0..6399
    const int rbg = g & (NRG - 1);           // 0..63
    const int strip = g >> 6;                // 0..99

    const short8* af = reinterpret_cast<const short8*>(a_frag);
    const short8* bf = reinterpret_cast<const short8*>(b_frag);

    short8 a[RBW];
    #pragma unroll
    for (int i = 0; i < RBW; ++i)
        a[i] = af[(rbg * RBW + i) * 64 + lane];

    f32x4 acc[RBW];
    #pragma unroll
    for (int i = 0; i < RBW; ++i) acc[i] = (f32x4){0.f, 0.f, 0.f, 0.f};
    const f32x4 czero = {0.f, 0.f, 0.f, 0.f};

    const int t0 = strip * TPW;
    short8 bcur = bf[t0 * 64 + lane];
    short8 bnxt = bf[(t0 + 1) * 64 + lane];

    #pragma unroll 2
    for (int i = 0; i < TPW; ++i) {
        const int tp = t0 + i + 2;
        short8 bpre = bf[(tp < NTILES ? tp : NTILES - 1) * 64 + lane];

        f32x4 d[RBW];
        #pragma unroll
        for (int k = 0; k < RBW; ++k)
            d[k] = __builtin_amdgcn_mfma_f32_16x16x32_bf16(a[k], bcur, czero, 0, 0, 0);

        #pragma unroll
        for (int k = 0; k < RBW; ++k) {
            acc[k].x += __expf(d[k].x);
            acc[k].y += __expf(d[k].y);
            acc[k].z += __expf(d[k].z);
            acc[k].w += __expf(d[k].w);
        }

        bcur = bnxt;
        bnxt = bpre;
    }

    // reduce each acc across the 16 column-lanes (lane&15)
    #pragma unroll
    for (int off = 1; off <= 8; off <<= 1) {
        #pragma unroll
        for (int k = 0; k < RBW; ++k) {
            acc[k].x += __shfl_xor(acc[k].x, off, 64);
            acc[k].y += __shfl_xor(acc[k].y, off, 64);
            acc[k].z += __shfl_xor(acc[k].z, off, 64);
            acc[k].w += __shfl_xor(acc[k].w, off, 64);
        }
    }

    if ((lane & 15) == 0) {
        #pragma unroll
        for (int k = 0; k < RBW; ++k) {
            const int rbase = (rbg * RBW + k) * 16 + (lane >> 4) * 4;
            float* p = partial + (size_t)strip * NROWS + rbase;
            p[0] = acc[k].x;
            p[1] = acc[k].y;
            p[2] = acc[k].z;
            p[3] = acc[k].w;
        }
    }
}

// ---------------------------------------------------------------------------
// Kernel B2: lse[r] = log( sum over 100 slots of partial[slot][r] )
// ---------------------------------------------------------------------------
__global__ __launch_bounds__(256) void k_reduce(
    const float* __restrict__ partial, float* __restrict__ lse)
{
    int r = blockIdx.x * 256 + threadIdx.x;
    if (r >= NROWS) return;
    float s = 0.f;
    #pragma unroll
    for (int k = 0; k < NSLOTS; ++k)
        s += partial[(size_t)k * NROWS + r];
    lse[r] = __logf(s);
}

// ---------------------------------------------------------------------------
// Kernel C: unchanged R9 structure (measured ~90 us @ 5.84 TB/s).
// ---------------------------------------------------------------------------
__global__ __launch_bounds__(256) void k_write(
    const float* __restrict__ h_table, const float* __restrict__ wo,
    const float* __restrict__ lse, float* __restrict__ out)
{
    const int tid = threadIdx.x;
    const int strip = blockIdx.x & (STRIPS - 1);
    const int chunk = blockIdx.x / STRIPS;
    const int v4 = strip * 256 + tid;
    const bool act = v4 < V4;
    const int r0 = chunk * ROWS_W;

    const f32x4* wo4 = reinterpret_cast<const f32x4*>(wo);
    f32x4 w[HID];
    #pragma unroll
    for (int j = 0; j < HID; ++j) {
        if (act) w[j] = wo4[j * V4 + v4];
        else     w[j] = (f32x4){0.f, 0.f, 0.f, 0.f};
    }

    f32x4* out4 = reinterpret_cast<f32x4*>(out);

    for (int rr = r0; rr < r0 + ROWS_W; rr += RGROUP) {
        f32x4 acc[RGROUP];
        #pragma unroll
        for (int i = 0; i < RGROUP; ++i) acc[i] = (f32x4){0.f, 0.f, 0.f, 0.f};

        #pragma unroll
        for (int q = 0; q < 4; ++q) {
            f32x4 h4[RGROUP];
            #pragma unroll
            for (int i = 0; i < RGROUP; ++i)
                h4[i] = *reinterpret_cast<const f32x4*>(h_table + (rr + i) * HID + q * 4);
            #pragma unroll
            for (int i = 0; i < RGROUP; ++i) {
                acc[i] += h4[i].x * w[q * 4 + 0];
                acc[i] += h4[i].y * w[q * 4 + 1];
                acc[i] += h4[i].z * w[q * 4 + 2];
                acc[i] += h4[i].w * w[q * 4 + 3];
            }
        }

        const f32x4 ls0 = *reinterpret_cast<const f32x4*>(lse + rr);
        const f32x4 ls1 = *reinterpret_cast<const f32x4*>(lse + rr + 4);

        if (act) {
            #pragma unroll
            for (int i = 0; i < RGROUP; ++i) {
                float l = (i < 4) ? ls0[i & 3] : ls1[i & 3];
                f32x4 o = acc[i] - l;
                out4[(long)(rr + i) * V4 + v4] = o;
            }
        }
    }
}

extern "C" void kernel_launch(void* const* d_in, const int* in_sizes, int n_in,
                              void* d_out, int out_size, void* d_ws, size_t ws_size,
                              hipStream_t stream) {
    const int*   idx    = (const int*)d_in[0];
    const float* lookup = (const float*)d_in[1];
    const float* wx     = (const float*)d_in[2];
    const float* wh     = (const float*)d_in[3];
    const float* wo     = (const float*)d_in[4];
    const float* h0     = (const float*)d_in[5];
    float* out = (float*)d_out;

    float* h_table = (float*)d_ws;                       // 4096*16 f32   (256 KB)
    float* lse     = h_table + NROWS * HID;              // 4096 f32
    float* partial = lse + NROWS;                        // 100*4096 f32  (1.6 MB)
    short* a_frag  = (short*)(partial + NSLOTS * NROWS); // 256*64*8 bf16 (256 KB)
    short* b_frag  = a_frag + NRB * 64 * 8;              // 2000*64*8 bf16 (2 MB)

    k_htable<<<NROWS / 256, 256, 0, stream>>>(idx, lookup, wx, wh, h0, h_table, a_frag);
    k_wpack<<<(NTILES * 64) / 256, 256, 0, stream>>>(wo, b_frag);
    k_expsum<<<(NRG * XSTRIPS) / 4, 256, 0, stream>>>(a_frag, b_frag, partial);
    k_reduce<<<NROWS / 256, 256, 0, stream>>>(partial, lse);
    k_write<<<STRIPS * CHUNKS, 256, 0, stream>>>(h_table, wo, lse, out);
}